// Round 1
// baseline (1861.871 us; speedup 1.0000x reference)
//
#include <hip/hip_runtime.h>

#define N_NODES   50000
#define N_EDGES   800000
#define DIM       128
#define N_GRAPHS  64
#define N_CLASSES 10

// ---- degrees + per-graph node counts (atomic histograms) --------------------
__global__ __launch_bounds__(256) void k_deg(const int* __restrict__ src,
                                             const int* __restrict__ dst,
                                             const int* __restrict__ gid,
                                             float* __restrict__ outdeg,
                                             float* __restrict__ indeg,
                                             float* __restrict__ cnt) {
    int i = blockIdx.x * 256 + threadIdx.x;
    if (i < N_EDGES) {
        atomicAdd(&outdeg[src[i]], 1.0f);
        atomicAdd(&indeg[dst[i]], 1.0f);
    }
    if (i < N_NODES) {
        atomicAdd(&cnt[gid[i]], 1.0f);
    }
}

// ---- edge scatter: agg[dst] += feat[src] * out_norm[src] --------------------
// 32 threads per edge, 4 dims (one float4) per thread. E*32 = 25.6M threads,
// exactly divisible by 256 -> no bounds check.
__global__ __launch_bounds__(256) void k_scatter(const int* __restrict__ src,
                                                 const int* __restrict__ dst,
                                                 const float* __restrict__ feat,
                                                 const float* __restrict__ outdeg,
                                                 float* __restrict__ agg) {
    int gidx = blockIdx.x * 256 + threadIdx.x;
    int e = gidx >> 5;
    int q = (gidx & 31) << 2;
    int s = src[e];
    int d = dst[e];
    float norm = rsqrtf(fmaxf(outdeg[s], 1.0f));
    float4 v = *reinterpret_cast<const float4*>(feat + s * DIM + q);
    float* ap = agg + d * DIM + q;
    atomicAdd(ap + 0, v.x * norm);
    atomicAdd(ap + 1, v.y * norm);
    atomicAdd(ap + 2, v.z * norm);
    atomicAdd(ap + 3, v.w * norm);
}

// ---- node transform: h = relu(in_norm * (agg @ W) + b); pooled[g] += h ------
// W (128x128 fp32 = 64KB) staged in LDS once per block; 64 nodes per block in
// 8 passes of 8 nodes. Each thread: 1 node (tid>>5), 4 output dims (float4 W
// reads from LDS). sW read: lanes 0-31 stride-4 words (conflict-free b128),
// lanes 32-63 same addrs (broadcast). srow read: wave-uniform per half-wave.
__global__ __launch_bounds__(256) void k_node(const float* __restrict__ agg,
                                              const float* __restrict__ indeg,
                                              const int* __restrict__ gid,
                                              const float* __restrict__ W,
                                              const float* __restrict__ b,
                                              float* __restrict__ pooled) {
    __shared__ float sW[DIM * DIM];
    __shared__ float srow[8][DIM];
    int tid = threadIdx.x;
    for (int i = tid; i < DIM * DIM; i += 256) sW[i] = W[i];

    int sel = tid >> 5;        // node slot within pass (0..7)
    int o   = (tid & 31) << 2; // output-dim base (0,4,...,124)
    float b0 = b[o], b1 = b[o + 1], b2 = b[o + 2], b3 = b[o + 3];

    int blockBase = blockIdx.x * 64;
    for (int p = 0; p < 8; ++p) {
        int base = blockBase + p * 8;
        __syncthreads();  // also covers sW load on first pass
        for (int i = tid; i < 8 * DIM; i += 256) {
            int n = base + (i >> 7);
            if (n < N_NODES) srow[i >> 7][i & 127] = agg[n * DIM + (i & 127)];
        }
        __syncthreads();
        int node = base + sel;
        if (node < N_NODES) {
            float a0 = 0.f, a1 = 0.f, a2 = 0.f, a3 = 0.f;
#pragma unroll 8
            for (int k = 0; k < DIM; ++k) {
                float r = srow[sel][k];
                float4 w = *reinterpret_cast<const float4*>(&sW[k * DIM + o]);
                a0 += r * w.x; a1 += r * w.y; a2 += r * w.z; a3 += r * w.w;
            }
            float innorm = rsqrtf(fmaxf(indeg[node], 1.0f));
            float h0 = fmaxf(a0 * innorm + b0, 0.0f);
            float h1 = fmaxf(a1 * innorm + b1, 0.0f);
            float h2 = fmaxf(a2 * innorm + b2, 0.0f);
            float h3 = fmaxf(a3 * innorm + b3, 0.0f);
            float* pp = pooled + gid[node] * DIM + o;
            atomicAdd(pp + 0, h0);
            atomicAdd(pp + 1, h1);
            atomicAdd(pp + 2, h2);
            atomicAdd(pp + 3, h3);
        }
    }
}

// ---- head: out[g,c] = dot(pooled[g]/cnt[g], W_head[:,c]) + b_head[c] --------
__global__ __launch_bounds__(256) void k_head(const float* __restrict__ pooled,
                                              const float* __restrict__ cnt,
                                              const float* __restrict__ Wh,
                                              const float* __restrict__ bh,
                                              float* __restrict__ out) {
    int i = blockIdx.x * 256 + threadIdx.x;
    if (i >= N_GRAPHS * N_CLASSES) return;
    int g = i / N_CLASSES, c = i % N_CLASSES;
    const float* pr = pooled + g * DIM;
    float s = 0.f;
#pragma unroll 8
    for (int k = 0; k < DIM; ++k) s += pr[k] * Wh[k * N_CLASSES + c];
    out[i] = s / fmaxf(cnt[g], 1.0f) + bh[c];
}

extern "C" void kernel_launch(void* const* d_in, const int* in_sizes, int n_in,
                              void* d_out, int out_size, void* d_ws, size_t ws_size,
                              hipStream_t stream) {
    const float* feat = (const float*)d_in[0];
    const int*   src  = (const int*)d_in[1];
    const int*   dst  = (const int*)d_in[2];
    const int*   gid  = (const int*)d_in[3];
    const float* W    = (const float*)d_in[4];
    const float* b    = (const float*)d_in[5];
    const float* Wh   = (const float*)d_in[6];
    const float* bh   = (const float*)d_in[7];
    float* out = (float*)d_out;

    // workspace layout (floats)
    float* agg    = (float*)d_ws;                       // N*D
    float* outdeg = agg + (size_t)N_NODES * DIM;        // N
    float* indeg  = outdeg + N_NODES;                   // N
    float* cnt    = indeg + N_NODES;                    // G
    float* pooled = cnt + N_GRAPHS;                     // G*D
    size_t zero_bytes =
        ((size_t)N_NODES * DIM + 2 * (size_t)N_NODES + N_GRAPHS + (size_t)N_GRAPHS * DIM)
        * sizeof(float);
    hipMemsetAsync(d_ws, 0, zero_bytes, stream);

    k_deg<<<(N_EDGES + 255) / 256, 256, 0, stream>>>(src, dst, gid, outdeg, indeg, cnt);
    k_scatter<<<(N_EDGES * 32) / 256, 256, 0, stream>>>(src, dst, feat, outdeg, agg);
    k_node<<<(N_NODES + 63) / 64, 256, 0, stream>>>(agg, indeg, gid, W, b, pooled);
    k_head<<<3, 256, 0, stream>>>(pooled, cnt, Wh, bh, out);
}

// Round 2
// 681.465 us; speedup vs baseline: 2.7322x; 2.7322x over previous
//
#include <hip/hip_runtime.h>

#define N_NODES   50000
#define N_EDGES   800000
#define DIM       128
#define N_GRAPHS  64
#define N_CLASSES 10
#define NB_N      ((N_NODES + 255) / 256)   // 196

// ---- degree histograms (int atomics) + per-graph node counts ----------------
__global__ __launch_bounds__(256) void k_deg(const int* __restrict__ src,
                                             const int* __restrict__ dst,
                                             const int* __restrict__ gid,
                                             unsigned* __restrict__ outdeg_i,
                                             unsigned* __restrict__ indeg_i,
                                             float* __restrict__ cnt) {
    int i = blockIdx.x * 256 + threadIdx.x;
    if (i < N_EDGES) {
        atomicAdd(&outdeg_i[src[i]], 1u);
        atomicAdd(&indeg_i[dst[i]], 1u);
    }
    if (i < N_NODES) {
        atomicAdd(&cnt[gid[i]], 1.0f);
    }
}

// ---- norms from counts ------------------------------------------------------
__global__ __launch_bounds__(256) void k_norm(const unsigned* __restrict__ outdeg_i,
                                              const unsigned* __restrict__ indeg_i,
                                              float* __restrict__ outnorm,
                                              float* __restrict__ innorm) {
    int i = blockIdx.x * 256 + threadIdx.x;
    if (i < N_NODES) {
        outnorm[i] = rsqrtf(fmaxf((float)outdeg_i[i], 1.0f));
        innorm[i]  = rsqrtf(fmaxf((float)indeg_i[i], 1.0f));
    }
}

// ---- exclusive scan over indeg_i -> row_ptr (3 kernels) ---------------------
__global__ __launch_bounds__(256) void k_scan1(const unsigned* __restrict__ indeg_i,
                                               unsigned* __restrict__ row_ptr,
                                               unsigned* __restrict__ blockSums) {
    __shared__ unsigned s[256];
    int t = threadIdx.x;
    int i = blockIdx.x * 256 + t;
    unsigned val = (i < N_NODES) ? indeg_i[i] : 0u;
    s[t] = val;
    __syncthreads();
    for (int off = 1; off < 256; off <<= 1) {
        unsigned x = (t >= off) ? s[t - off] : 0u;
        __syncthreads();
        s[t] += x;
        __syncthreads();
    }
    if (i < N_NODES) row_ptr[i] = s[t] - val;     // block-local exclusive
    if (t == 255) blockSums[blockIdx.x] = s[255];
}

__global__ __launch_bounds__(256) void k_scan2(unsigned* __restrict__ blockSums,
                                               unsigned* __restrict__ blockOff) {
    __shared__ unsigned s[256];
    int t = threadIdx.x;
    unsigned val = (t < NB_N) ? blockSums[t] : 0u;
    s[t] = val;
    __syncthreads();
    for (int off = 1; off < 256; off <<= 1) {
        unsigned x = (t >= off) ? s[t - off] : 0u;
        __syncthreads();
        s[t] += x;
        __syncthreads();
    }
    if (t < NB_N) blockOff[t] = s[t] - val;       // exclusive over block sums
}

__global__ __launch_bounds__(256) void k_scan3(unsigned* __restrict__ row_ptr,
                                               const unsigned* __restrict__ blockOff) {
    int i = blockIdx.x * 256 + threadIdx.x;
    if (i < N_NODES) row_ptr[i] += blockOff[i >> 8];
}

// ---- bucket edges by dst ----------------------------------------------------
__global__ __launch_bounds__(256) void k_bucket(const int* __restrict__ src,
                                                const int* __restrict__ dst,
                                                const unsigned* __restrict__ row_ptr,
                                                unsigned* __restrict__ cursor,
                                                int* __restrict__ bsrc) {
    int e = blockIdx.x * 256 + threadIdx.x;
    if (e < N_EDGES) {
        int d = dst[e];
        unsigned p = atomicAdd(&cursor[d], 1u);
        bsrc[row_ptr[d] + p] = src[e];
    }
}

// ---- gather-sum: agg[n] = innorm[n] * sum_{e: dst=n} feat[src_e]*outnorm[src_e]
// One wave per node; 2 edges per iteration (half-wave × float4 per lane).
__global__ __launch_bounds__(256) void k_gather(const int* __restrict__ bsrc,
                                                const unsigned* __restrict__ row_ptr,
                                                const unsigned* __restrict__ indeg_i,
                                                const float* __restrict__ feat,
                                                const float* __restrict__ outnorm,
                                                const float* __restrict__ innorm,
                                                float* __restrict__ agg) {
    int tid = threadIdx.x;
    int wave = tid >> 6;
    int lane = tid & 63;
    int node = blockIdx.x * 4 + wave;
    if (node >= N_NODES) return;
    unsigned start = row_ptr[node];
    unsigned deg   = indeg_i[node];
    int half = lane >> 5;
    int q    = (lane & 31) << 2;
    float4 acc = {0.f, 0.f, 0.f, 0.f};
    for (unsigned j = 0; j < deg; j += 2) {
        unsigned jj = j + half;
        bool valid = (jj < deg);
        int s = bsrc[start + (valid ? jj : 0u)];
        float nrm = valid ? outnorm[s] : 0.0f;
        float4 v = *reinterpret_cast<const float4*>(feat + (size_t)s * DIM + q);
        acc.x += v.x * nrm;
        acc.y += v.y * nrm;
        acc.z += v.z * nrm;
        acc.w += v.w * nrm;
    }
    acc.x += __shfl_down(acc.x, 32);
    acc.y += __shfl_down(acc.y, 32);
    acc.z += __shfl_down(acc.z, 32);
    acc.w += __shfl_down(acc.w, 32);
    if (half == 0) {
        float innrm = innorm[node];
        float4 r = {acc.x * innrm, acc.y * innrm, acc.z * innrm, acc.w * innrm};
        *reinterpret_cast<float4*>(agg + (size_t)node * DIM + q) = r;
    }
}

// ---- node transform: h = relu(agg @ W + b); pooled[g] += h ------------------
__global__ __launch_bounds__(256) void k_node(const float* __restrict__ agg,
                                              const int* __restrict__ gid,
                                              const float* __restrict__ W,
                                              const float* __restrict__ b,
                                              float* __restrict__ pooled) {
    __shared__ float sW[DIM * DIM];
    __shared__ float srow[8][DIM];
    int tid = threadIdx.x;
    for (int i = tid; i < DIM * DIM; i += 256) sW[i] = W[i];

    int sel = tid >> 5;        // node slot within pass (0..7)
    int o   = (tid & 31) << 2; // output-dim base
    float b0 = b[o], b1 = b[o + 1], b2 = b[o + 2], b3 = b[o + 3];

    int blockBase = blockIdx.x * 64;
    for (int p = 0; p < 8; ++p) {
        int base = blockBase + p * 8;
        __syncthreads();
        for (int i = tid; i < 8 * DIM; i += 256) {
            int n = base + (i >> 7);
            if (n < N_NODES) srow[i >> 7][i & 127] = agg[n * DIM + (i & 127)];
        }
        __syncthreads();
        int node = base + sel;
        if (node < N_NODES) {
            float a0 = 0.f, a1 = 0.f, a2 = 0.f, a3 = 0.f;
#pragma unroll 8
            for (int k = 0; k < DIM; ++k) {
                float r = srow[sel][k];
                float4 w = *reinterpret_cast<const float4*>(&sW[k * DIM + o]);
                a0 += r * w.x; a1 += r * w.y; a2 += r * w.z; a3 += r * w.w;
            }
            float h0 = fmaxf(a0 + b0, 0.0f);
            float h1 = fmaxf(a1 + b1, 0.0f);
            float h2 = fmaxf(a2 + b2, 0.0f);
            float h3 = fmaxf(a3 + b3, 0.0f);
            float* pp = pooled + gid[node] * DIM + o;
            atomicAdd(pp + 0, h0);
            atomicAdd(pp + 1, h1);
            atomicAdd(pp + 2, h2);
            atomicAdd(pp + 3, h3);
        }
    }
}

// ---- head -------------------------------------------------------------------
__global__ __launch_bounds__(256) void k_head(const float* __restrict__ pooled,
                                              const float* __restrict__ cnt,
                                              const float* __restrict__ Wh,
                                              const float* __restrict__ bh,
                                              float* __restrict__ out) {
    int i = blockIdx.x * 256 + threadIdx.x;
    if (i >= N_GRAPHS * N_CLASSES) return;
    int g = i / N_CLASSES, c = i % N_CLASSES;
    const float* pr = pooled + g * DIM;
    float s = 0.f;
#pragma unroll 8
    for (int k = 0; k < DIM; ++k) s += pr[k] * Wh[k * N_CLASSES + c];
    out[i] = s / fmaxf(cnt[g], 1.0f) + bh[c];
}

extern "C" void kernel_launch(void* const* d_in, const int* in_sizes, int n_in,
                              void* d_out, int out_size, void* d_ws, size_t ws_size,
                              hipStream_t stream) {
    const float* feat = (const float*)d_in[0];
    const int*   src  = (const int*)d_in[1];
    const int*   dst  = (const int*)d_in[2];
    const int*   gid  = (const int*)d_in[3];
    const float* W    = (const float*)d_in[4];
    const float* b    = (const float*)d_in[5];
    const float* Wh   = (const float*)d_in[6];
    const float* bh   = (const float*)d_in[7];
    float* out = (float*)d_out;

    // ---- workspace layout (4-byte elements) ----
    // zeroed region first: cursor, outdeg_i, indeg_i, cnt, pooled
    unsigned* cursor   = (unsigned*)d_ws;
    unsigned* outdeg_i = cursor + N_NODES;
    unsigned* indeg_i  = outdeg_i + N_NODES;
    float*    cnt      = (float*)(indeg_i + N_NODES);
    float*    pooled   = cnt + N_GRAPHS;
    size_t zero_bytes = ((size_t)3 * N_NODES + N_GRAPHS + (size_t)N_GRAPHS * DIM) * 4;
    // non-zeroed region
    unsigned* row_ptr   = (unsigned*)(pooled + (size_t)N_GRAPHS * DIM);
    unsigned* blockSums = row_ptr + N_NODES;
    unsigned* blockOff  = blockSums + 256;
    int*      bsrc      = (int*)(blockOff + 256);
    float*    outnorm   = (float*)(bsrc + N_EDGES);
    float*    innorm    = outnorm + N_NODES;
    float*    agg       = innorm + N_NODES;

    hipMemsetAsync(d_ws, 0, zero_bytes, stream);

    k_deg   <<<(N_EDGES + 255) / 256, 256, 0, stream>>>(src, dst, gid, outdeg_i, indeg_i, cnt);
    k_norm  <<<NB_N, 256, 0, stream>>>(outdeg_i, indeg_i, outnorm, innorm);
    k_scan1 <<<NB_N, 256, 0, stream>>>(indeg_i, row_ptr, blockSums);
    k_scan2 <<<1, 256, 0, stream>>>(blockSums, blockOff);
    k_scan3 <<<NB_N, 256, 0, stream>>>(row_ptr, blockOff);
    k_bucket<<<(N_EDGES + 255) / 256, 256, 0, stream>>>(src, dst, row_ptr, cursor, bsrc);
    k_gather<<<(N_NODES + 3) / 4, 256, 0, stream>>>(bsrc, row_ptr, indeg_i, feat, outnorm, innorm, agg);
    k_node  <<<(N_NODES + 63) / 64, 256, 0, stream>>>(agg, gid, W, b, pooled);
    k_head  <<<3, 256, 0, stream>>>(pooled, cnt, Wh, bh, out);
}

// Round 3
// 423.088 us; speedup vs baseline: 4.4007x; 1.6107x over previous
//
#include <hip/hip_runtime.h>

#define N_NODES   50000
#define N_EDGES   800000
#define DIM       128
#define N_GRAPHS  64
#define N_CLASSES 10
#define NB_N      ((N_NODES + 255) / 256)   // 196

// ---- degree histograms (random-address int atomics) + graph boundaries -----
// graph_ids is SORTED: boundaries found by neighbor compare, no atomics.
__global__ __launch_bounds__(256) void k_deg(const int* __restrict__ src,
                                             const int* __restrict__ dst,
                                             const int* __restrict__ gid,
                                             unsigned* __restrict__ outdeg_i,
                                             unsigned* __restrict__ indeg_i,
                                             int* __restrict__ start) {
    int i = blockIdx.x * 256 + threadIdx.x;
    if (i < N_EDGES) {
        atomicAdd(&outdeg_i[src[i]], 1u);
        atomicAdd(&indeg_i[dst[i]], 1u);
    }
    if (i < N_NODES) {
        int g = gid[i];
        if (i == 0) {
            for (int x = 0; x <= g; ++x) start[x] = 0;
        } else {
            int gp = gid[i - 1];
            if (gp != g)
                for (int x = gp + 1; x <= g; ++x) start[x] = i;
        }
        if (i == N_NODES - 1)
            for (int x = g + 1; x <= N_GRAPHS; ++x) start[x] = N_NODES;
    }
}

// ---- norms from counts ------------------------------------------------------
__global__ __launch_bounds__(256) void k_norm(const unsigned* __restrict__ outdeg_i,
                                              const unsigned* __restrict__ indeg_i,
                                              float* __restrict__ outnorm,
                                              float* __restrict__ innorm) {
    int i = blockIdx.x * 256 + threadIdx.x;
    if (i < N_NODES) {
        outnorm[i] = rsqrtf(fmaxf((float)outdeg_i[i], 1.0f));
        innorm[i]  = rsqrtf(fmaxf((float)indeg_i[i], 1.0f));
    }
}

// ---- exclusive scan over indeg_i -> row_ptr (3 kernels) ---------------------
__global__ __launch_bounds__(256) void k_scan1(const unsigned* __restrict__ indeg_i,
                                               unsigned* __restrict__ row_ptr,
                                               unsigned* __restrict__ blockSums) {
    __shared__ unsigned s[256];
    int t = threadIdx.x;
    int i = blockIdx.x * 256 + t;
    unsigned val = (i < N_NODES) ? indeg_i[i] : 0u;
    s[t] = val;
    __syncthreads();
    for (int off = 1; off < 256; off <<= 1) {
        unsigned x = (t >= off) ? s[t - off] : 0u;
        __syncthreads();
        s[t] += x;
        __syncthreads();
    }
    if (i < N_NODES) row_ptr[i] = s[t] - val;
    if (t == 255) blockSums[blockIdx.x] = s[255];
}

__global__ __launch_bounds__(256) void k_scan2(unsigned* __restrict__ blockSums,
                                               unsigned* __restrict__ blockOff) {
    __shared__ unsigned s[256];
    int t = threadIdx.x;
    unsigned val = (t < NB_N) ? blockSums[t] : 0u;
    s[t] = val;
    __syncthreads();
    for (int off = 1; off < 256; off <<= 1) {
        unsigned x = (t >= off) ? s[t - off] : 0u;
        __syncthreads();
        s[t] += x;
        __syncthreads();
    }
    if (t < NB_N) blockOff[t] = s[t] - val;
}

__global__ __launch_bounds__(256) void k_scan3(unsigned* __restrict__ row_ptr,
                                               const unsigned* __restrict__ blockOff) {
    int i = blockIdx.x * 256 + threadIdx.x;
    if (i < N_NODES) row_ptr[i] += blockOff[i >> 8];
}

// ---- bucket edges by dst ----------------------------------------------------
__global__ __launch_bounds__(256) void k_bucket(const int* __restrict__ src,
                                                const int* __restrict__ dst,
                                                const unsigned* __restrict__ row_ptr,
                                                unsigned* __restrict__ cursor,
                                                int* __restrict__ bsrc) {
    int e = blockIdx.x * 256 + threadIdx.x;
    if (e < N_EDGES) {
        int d = dst[e];
        unsigned p = atomicAdd(&cursor[d], 1u);
        bsrc[row_ptr[d] + p] = src[e];
    }
}

// ---- gather-sum: agg[n] = innorm[n] * sum_{e: dst=n} feat[src_e]*outnorm[src_e]
__global__ __launch_bounds__(256) void k_gather(const int* __restrict__ bsrc,
                                                const unsigned* __restrict__ row_ptr,
                                                const unsigned* __restrict__ indeg_i,
                                                const float* __restrict__ feat,
                                                const float* __restrict__ outnorm,
                                                const float* __restrict__ innorm,
                                                float* __restrict__ agg) {
    int tid = threadIdx.x;
    int wave = tid >> 6;
    int lane = tid & 63;
    int node = blockIdx.x * 4 + wave;
    if (node >= N_NODES) return;
    unsigned start = row_ptr[node];
    unsigned deg   = indeg_i[node];
    int half = lane >> 5;
    int q    = (lane & 31) << 2;
    float4 acc = {0.f, 0.f, 0.f, 0.f};
    for (unsigned j = 0; j < deg; j += 2) {
        unsigned jj = j + half;
        bool valid = (jj < deg);
        int s = bsrc[start + (valid ? jj : 0u)];
        float nrm = valid ? outnorm[s] : 0.0f;
        float4 v = *reinterpret_cast<const float4*>(feat + (size_t)s * DIM + q);
        acc.x += v.x * nrm;
        acc.y += v.y * nrm;
        acc.z += v.z * nrm;
        acc.w += v.w * nrm;
    }
    acc.x += __shfl_down(acc.x, 32);
    acc.y += __shfl_down(acc.y, 32);
    acc.z += __shfl_down(acc.z, 32);
    acc.w += __shfl_down(acc.w, 32);
    if (half == 0) {
        float innrm = innorm[node];
        float4 r = {acc.x * innrm, acc.y * innrm, acc.z * innrm, acc.w * innrm};
        *reinterpret_cast<float4*>(agg + (size_t)node * DIM + q) = r;
    }
}

// ---- node transform: h = relu(agg @ W + b), written IN PLACE over agg -------
// Safe: each node's h depends only on its own agg row, staged into LDS before
// the overwrite, and nodes are partitioned across blocks.
__global__ __launch_bounds__(256) void k_node(float* __restrict__ agg,
                                              const float* __restrict__ W,
                                              const float* __restrict__ b) {
    __shared__ float sW[DIM * DIM];
    __shared__ float srow[8][DIM];
    int tid = threadIdx.x;
    for (int i = tid; i < DIM * DIM; i += 256) sW[i] = W[i];

    int sel = tid >> 5;
    int o   = (tid & 31) << 2;
    float b0 = b[o], b1 = b[o + 1], b2 = b[o + 2], b3 = b[o + 3];

    int blockBase = blockIdx.x * 64;
    for (int p = 0; p < 8; ++p) {
        int base = blockBase + p * 8;
        __syncthreads();
        for (int i = tid; i < 8 * DIM; i += 256) {
            int n = base + (i >> 7);
            if (n < N_NODES) srow[i >> 7][i & 127] = agg[n * DIM + (i & 127)];
        }
        __syncthreads();
        int node = base + sel;
        if (node < N_NODES) {
            float a0 = 0.f, a1 = 0.f, a2 = 0.f, a3 = 0.f;
#pragma unroll 8
            for (int k = 0; k < DIM; ++k) {
                float r = srow[sel][k];
                float4 w = *reinterpret_cast<const float4*>(&sW[k * DIM + o]);
                a0 += r * w.x; a1 += r * w.y; a2 += r * w.z; a3 += r * w.w;
            }
            float4 h;
            h.x = fmaxf(a0 + b0, 0.0f);
            h.y = fmaxf(a1 + b1, 0.0f);
            h.z = fmaxf(a2 + b2, 0.0f);
            h.w = fmaxf(a3 + b3, 0.0f);
            *reinterpret_cast<float4*>(agg + (size_t)node * DIM + o) = h;
        }
    }
}

// ---- graph mean-pool: one block per graph, contiguous node range ------------
__global__ __launch_bounds__(256) void k_pool(const float* __restrict__ h,
                                              const int* __restrict__ start,
                                              float* __restrict__ pooled) {
    __shared__ float red[256];
    int g = blockIdx.x;
    int t = threadIdx.x;
    int s = start[g], e = start[g + 1];
    int dim  = t & 127;
    int half = t >> 7;
    float acc = 0.f;
    for (int n = s + half; n < e; n += 2)
        acc += h[(size_t)n * DIM + dim];
    red[t] = acc;
    __syncthreads();
    if (t < 128) {
        float cntf = fmaxf((float)(e - s), 1.0f);
        pooled[g * DIM + dim] = (red[t] + red[t + 128]) / cntf;
    }
}

// ---- head: out = pooled @ W_head + b_head -----------------------------------
__global__ __launch_bounds__(256) void k_head(const float* __restrict__ pooled,
                                              const float* __restrict__ Wh,
                                              const float* __restrict__ bh,
                                              float* __restrict__ out) {
    int i = blockIdx.x * 256 + threadIdx.x;
    if (i >= N_GRAPHS * N_CLASSES) return;
    int g = i / N_CLASSES, c = i % N_CLASSES;
    const float* pr = pooled + g * DIM;
    float s = 0.f;
#pragma unroll 8
    for (int k = 0; k < DIM; ++k) s += pr[k] * Wh[k * N_CLASSES + c];
    out[i] = s + bh[c];
}

extern "C" void kernel_launch(void* const* d_in, const int* in_sizes, int n_in,
                              void* d_out, int out_size, void* d_ws, size_t ws_size,
                              hipStream_t stream) {
    const float* feat = (const float*)d_in[0];
    const int*   src  = (const int*)d_in[1];
    const int*   dst  = (const int*)d_in[2];
    const int*   gid  = (const int*)d_in[3];
    const float* W    = (const float*)d_in[4];
    const float* b    = (const float*)d_in[5];
    const float* Wh   = (const float*)d_in[6];
    const float* bh   = (const float*)d_in[7];
    float* out = (float*)d_out;

    // ---- workspace layout (4-byte elements) ----
    // zeroed: cursor, outdeg_i, indeg_i
    unsigned* cursor   = (unsigned*)d_ws;
    unsigned* outdeg_i = cursor + N_NODES;
    unsigned* indeg_i  = outdeg_i + N_NODES;
    size_t zero_bytes = (size_t)3 * N_NODES * 4;
    // non-zeroed
    int*      start     = (int*)(indeg_i + N_NODES);        // G+1
    unsigned* row_ptr   = (unsigned*)(start + N_GRAPHS + 1);
    unsigned* blockSums = row_ptr + N_NODES;
    unsigned* blockOff  = blockSums + 256;
    int*      bsrc      = (int*)(blockOff + 256);
    float*    outnorm   = (float*)(bsrc + N_EDGES);
    float*    innorm    = outnorm + N_NODES;
    float*    agg       = innorm + N_NODES;                  // N*D, reused as h
    float*    pooled    = agg + (size_t)N_NODES * DIM;       // G*D

    hipMemsetAsync(d_ws, 0, zero_bytes, stream);

    k_deg   <<<(N_EDGES + 255) / 256, 256, 0, stream>>>(src, dst, gid, outdeg_i, indeg_i, start);
    k_norm  <<<NB_N, 256, 0, stream>>>(outdeg_i, indeg_i, outnorm, innorm);
    k_scan1 <<<NB_N, 256, 0, stream>>>(indeg_i, row_ptr, blockSums);
    k_scan2 <<<1, 256, 0, stream>>>(blockSums, blockOff);
    k_scan3 <<<NB_N, 256, 0, stream>>>(row_ptr, blockOff);
    k_bucket<<<(N_EDGES + 255) / 256, 256, 0, stream>>>(src, dst, row_ptr, cursor, bsrc);
    k_gather<<<(N_NODES + 3) / 4, 256, 0, stream>>>(bsrc, row_ptr, indeg_i, feat, outnorm, innorm, agg);
    k_node  <<<(N_NODES + 63) / 64, 256, 0, stream>>>(agg, W, b);
    k_pool  <<<N_GRAPHS, 256, 0, stream>>>(agg, start, pooled);
    k_head  <<<3, 256, 0, stream>>>(pooled, Wh, bh, out);
}

// Round 4
// 337.039 us; speedup vs baseline: 5.5242x; 1.2553x over previous
//
#include <hip/hip_runtime.h>

#define N_NODES   50000
#define N_EDGES   800000
#define DIM       128
#define N_GRAPHS  64
#define N_CLASSES 10
#define NB_N      ((N_NODES + 255) / 256)   // 196
#define NCHUNK    16

// ---- degree histograms (random-address int atomics) + graph boundaries -----
// graph_ids is SORTED: boundaries found by neighbor compare, no atomics.
__global__ __launch_bounds__(256) void k_deg(const int* __restrict__ src,
                                             const int* __restrict__ dst,
                                             const int* __restrict__ gid,
                                             unsigned* __restrict__ outdeg_i,
                                             unsigned* __restrict__ indeg_i,
                                             int* __restrict__ start) {
    int i = blockIdx.x * 256 + threadIdx.x;
    if (i < N_EDGES) {
        atomicAdd(&outdeg_i[src[i]], 1u);
        atomicAdd(&indeg_i[dst[i]], 1u);
    }
    if (i < N_NODES) {
        int g = gid[i];
        if (i == 0) {
            for (int x = 0; x <= g; ++x) start[x] = 0;
        } else {
            int gp = gid[i - 1];
            if (gp != g)
                for (int x = gp + 1; x <= g; ++x) start[x] = i;
        }
        if (i == N_NODES - 1)
            for (int x = g + 1; x <= N_GRAPHS; ++x) start[x] = N_NODES;
    }
}

// ---- norms from counts ------------------------------------------------------
__global__ __launch_bounds__(256) void k_norm(const unsigned* __restrict__ outdeg_i,
                                              const unsigned* __restrict__ indeg_i,
                                              float* __restrict__ outnorm,
                                              float* __restrict__ innorm) {
    int i = blockIdx.x * 256 + threadIdx.x;
    if (i < N_NODES) {
        outnorm[i] = rsqrtf(fmaxf((float)outdeg_i[i], 1.0f));
        innorm[i]  = rsqrtf(fmaxf((float)indeg_i[i], 1.0f));
    }
}

// ---- exclusive scan over indeg_i -> row_ptr (3 kernels) ---------------------
__global__ __launch_bounds__(256) void k_scan1(const unsigned* __restrict__ indeg_i,
                                               unsigned* __restrict__ row_ptr,
                                               unsigned* __restrict__ blockSums) {
    __shared__ unsigned s[256];
    int t = threadIdx.x;
    int i = blockIdx.x * 256 + t;
    unsigned val = (i < N_NODES) ? indeg_i[i] : 0u;
    s[t] = val;
    __syncthreads();
    for (int off = 1; off < 256; off <<= 1) {
        unsigned x = (t >= off) ? s[t - off] : 0u;
        __syncthreads();
        s[t] += x;
        __syncthreads();
    }
    if (i < N_NODES) row_ptr[i] = s[t] - val;
    if (t == 255) blockSums[blockIdx.x] = s[255];
}

__global__ __launch_bounds__(256) void k_scan2(unsigned* __restrict__ blockSums,
                                               unsigned* __restrict__ blockOff) {
    __shared__ unsigned s[256];
    int t = threadIdx.x;
    unsigned val = (t < NB_N) ? blockSums[t] : 0u;
    s[t] = val;
    __syncthreads();
    for (int off = 1; off < 256; off <<= 1) {
        unsigned x = (t >= off) ? s[t - off] : 0u;
        __syncthreads();
        s[t] += x;
        __syncthreads();
    }
    if (t < NB_N) blockOff[t] = s[t] - val;
}

__global__ __launch_bounds__(256) void k_scan3(unsigned* __restrict__ row_ptr,
                                               const unsigned* __restrict__ blockOff) {
    int i = blockIdx.x * 256 + threadIdx.x;
    if (i < N_NODES) row_ptr[i] += blockOff[i >> 8];
}

// ---- bucket edges by dst ----------------------------------------------------
__global__ __launch_bounds__(256) void k_bucket(const int* __restrict__ src,
                                                const int* __restrict__ dst,
                                                const unsigned* __restrict__ row_ptr,
                                                unsigned* __restrict__ cursor,
                                                int* __restrict__ bsrc) {
    int e = blockIdx.x * 256 + threadIdx.x;
    if (e < N_EDGES) {
        int d = dst[e];
        unsigned p = atomicAdd(&cursor[d], 1u);
        bsrc[row_ptr[d] + p] = src[e];
    }
}

// ---- gather-sum: agg[n] = innorm[n] * sum_{e: dst=n} feat[src_e]*outnorm[src_e]
__global__ __launch_bounds__(256) void k_gather(const int* __restrict__ bsrc,
                                                const unsigned* __restrict__ row_ptr,
                                                const unsigned* __restrict__ indeg_i,
                                                const float* __restrict__ feat,
                                                const float* __restrict__ outnorm,
                                                const float* __restrict__ innorm,
                                                float* __restrict__ agg) {
    int tid = threadIdx.x;
    int wave = tid >> 6;
    int lane = tid & 63;
    int node = blockIdx.x * 4 + wave;
    if (node >= N_NODES) return;
    unsigned start = row_ptr[node];
    unsigned deg   = indeg_i[node];
    int half = lane >> 5;
    int q    = (lane & 31) << 2;
    float4 acc = {0.f, 0.f, 0.f, 0.f};
    for (unsigned j = 0; j < deg; j += 2) {
        unsigned jj = j + half;
        bool valid = (jj < deg);
        int s = bsrc[start + (valid ? jj : 0u)];
        float nrm = valid ? outnorm[s] : 0.0f;
        float4 v = *reinterpret_cast<const float4*>(feat + (size_t)s * DIM + q);
        acc.x += v.x * nrm;
        acc.y += v.y * nrm;
        acc.z += v.z * nrm;
        acc.w += v.w * nrm;
    }
    acc.x += __shfl_down(acc.x, 32);
    acc.y += __shfl_down(acc.y, 32);
    acc.z += __shfl_down(acc.z, 32);
    acc.w += __shfl_down(acc.w, 32);
    if (half == 0) {
        float innrm = innorm[node];
        float4 r = {acc.x * innrm, acc.y * innrm, acc.z * innrm, acc.w * innrm};
        *reinterpret_cast<float4*>(agg + (size_t)node * DIM + q) = r;
    }
}

// ---- node transform: h = relu(agg @ W + b), written IN PLACE over agg -------
__global__ __launch_bounds__(256) void k_node(float* __restrict__ agg,
                                              const float* __restrict__ W,
                                              const float* __restrict__ b) {
    __shared__ float sW[DIM * DIM];
    __shared__ float srow[8][DIM];
    int tid = threadIdx.x;
    for (int i = tid; i < DIM * DIM; i += 256) sW[i] = W[i];

    int sel = tid >> 5;
    int o   = (tid & 31) << 2;
    float b0 = b[o], b1 = b[o + 1], b2 = b[o + 2], b3 = b[o + 3];

    int blockBase = blockIdx.x * 64;
    for (int p = 0; p < 8; ++p) {
        int base = blockBase + p * 8;
        __syncthreads();
        for (int i = tid; i < 8 * DIM; i += 256) {
            int n = base + (i >> 7);
            if (n < N_NODES) srow[i >> 7][i & 127] = agg[n * DIM + (i & 127)];
        }
        __syncthreads();
        int node = base + sel;
        if (node < N_NODES) {
            float a0 = 0.f, a1 = 0.f, a2 = 0.f, a3 = 0.f;
#pragma unroll 8
            for (int k = 0; k < DIM; ++k) {
                float r = srow[sel][k];
                float4 w = *reinterpret_cast<const float4*>(&sW[k * DIM + o]);
                a0 += r * w.x; a1 += r * w.y; a2 += r * w.z; a3 += r * w.w;
            }
            float4 h;
            h.x = fmaxf(a0 + b0, 0.0f);
            h.y = fmaxf(a1 + b1, 0.0f);
            h.z = fmaxf(a2 + b2, 0.0f);
            h.w = fmaxf(a3 + b3, 0.0f);
            *reinterpret_cast<float4*>(agg + (size_t)node * DIM + o) = h;
        }
    }
}

// ---- graph sum-pool, parallel: grid (G, NCHUNK); atomics into zeroed pooled -
__global__ __launch_bounds__(256) void k_pool(const float* __restrict__ h,
                                              const int* __restrict__ start,
                                              float* __restrict__ pooled) {
    __shared__ float red[8][DIM];
    int g = blockIdx.x;
    int chunk = blockIdx.y;
    int t = threadIdx.x;
    int slot = t >> 5;         // 0..7 node slots
    int q    = (t & 31) << 2;  // dim base
    int s = start[g], e = start[g + 1];
    float4 acc = {0.f, 0.f, 0.f, 0.f};
    for (int n = s + chunk * 8 + slot; n < e; n += NCHUNK * 8) {
        float4 v = *reinterpret_cast<const float4*>(h + (size_t)n * DIM + q);
        acc.x += v.x; acc.y += v.y; acc.z += v.z; acc.w += v.w;
    }
    *reinterpret_cast<float4*>(&red[slot][q]) = acc;
    __syncthreads();
    if (t < DIM) {
        float sum = 0.f;
#pragma unroll
        for (int r = 0; r < 8; ++r) sum += red[r][t];
        atomicAdd(&pooled[g * DIM + t], sum);
    }
}

// ---- head: out = (pooled/cnt) @ W_head + b_head -----------------------------
__global__ __launch_bounds__(256) void k_head(const float* __restrict__ pooled,
                                              const int* __restrict__ start,
                                              const float* __restrict__ Wh,
                                              const float* __restrict__ bh,
                                              float* __restrict__ out) {
    int i = blockIdx.x * 256 + threadIdx.x;
    if (i >= N_GRAPHS * N_CLASSES) return;
    int g = i / N_CLASSES, c = i % N_CLASSES;
    const float* pr = pooled + g * DIM;
    float s = 0.f;
#pragma unroll 8
    for (int k = 0; k < DIM; ++k) s += pr[k] * Wh[k * N_CLASSES + c];
    float cntf = fmaxf((float)(start[g + 1] - start[g]), 1.0f);
    out[i] = s / cntf + bh[c];
}

extern "C" void kernel_launch(void* const* d_in, const int* in_sizes, int n_in,
                              void* d_out, int out_size, void* d_ws, size_t ws_size,
                              hipStream_t stream) {
    const float* feat = (const float*)d_in[0];
    const int*   src  = (const int*)d_in[1];
    const int*   dst  = (const int*)d_in[2];
    const int*   gid  = (const int*)d_in[3];
    const float* W    = (const float*)d_in[4];
    const float* b    = (const float*)d_in[5];
    const float* Wh   = (const float*)d_in[6];
    const float* bh   = (const float*)d_in[7];
    float* out = (float*)d_out;

    // ---- workspace layout (4-byte elements) ----
    // zeroed: cursor, outdeg_i, indeg_i, pooled
    unsigned* cursor   = (unsigned*)d_ws;
    unsigned* outdeg_i = cursor + N_NODES;
    unsigned* indeg_i  = outdeg_i + N_NODES;
    float*    pooled   = (float*)(indeg_i + N_NODES);        // G*D
    size_t zero_bytes = ((size_t)3 * N_NODES + (size_t)N_GRAPHS * DIM) * 4;
    // non-zeroed
    int*      start     = (int*)(pooled + (size_t)N_GRAPHS * DIM); // G+1
    unsigned* row_ptr   = (unsigned*)(start + N_GRAPHS + 1);
    unsigned* blockSums = row_ptr + N_NODES;
    unsigned* blockOff  = blockSums + 256;
    int*      bsrc      = (int*)(blockOff + 256);
    float*    outnorm   = (float*)(bsrc + N_EDGES);
    float*    innorm    = outnorm + N_NODES;
    float*    agg       = innorm + N_NODES;                  // N*D, reused as h

    hipMemsetAsync(d_ws, 0, zero_bytes, stream);

    k_deg   <<<(N_EDGES + 255) / 256, 256, 0, stream>>>(src, dst, gid, outdeg_i, indeg_i, start);
    k_norm  <<<NB_N, 256, 0, stream>>>(outdeg_i, indeg_i, outnorm, innorm);
    k_scan1 <<<NB_N, 256, 0, stream>>>(indeg_i, row_ptr, blockSums);
    k_scan2 <<<1, 256, 0, stream>>>(blockSums, blockOff);
    k_scan3 <<<NB_N, 256, 0, stream>>>(row_ptr, blockOff);
    k_bucket<<<(N_EDGES + 255) / 256, 256, 0, stream>>>(src, dst, row_ptr, cursor, bsrc);
    k_gather<<<(N_NODES + 3) / 4, 256, 0, stream>>>(bsrc, row_ptr, indeg_i, feat, outnorm, innorm, agg);
    k_node  <<<(N_NODES + 63) / 64, 256, 0, stream>>>(agg, W, b);
    dim3 pg(N_GRAPHS, NCHUNK);
    k_pool  <<<pg, 256, 0, stream>>>(agg, start, pooled);
    k_head  <<<3, 256, 0, stream>>>(pooled, start, Wh, bh, out);
}

// Round 5
// 311.754 us; speedup vs baseline: 5.9722x; 1.0811x over previous
//
#include <hip/hip_runtime.h>

#define N_NODES   50000
#define N_EDGES   800000
#define DIM       128
#define N_GRAPHS  64
#define N_CLASSES 10
#define NB_N      ((N_NODES + 255) / 256)   // 196
#define NCHUNK    16
#define NPB       128   // nodes per block in k_node
#define PASSN     32    // nodes staged per pass

// ---- degree histograms (random-address int atomics) + graph boundaries -----
__global__ __launch_bounds__(256) void k_deg(const int* __restrict__ src,
                                             const int* __restrict__ dst,
                                             const int* __restrict__ gid,
                                             unsigned* __restrict__ outdeg_i,
                                             unsigned* __restrict__ indeg_i,
                                             int* __restrict__ start) {
    int i = blockIdx.x * 256 + threadIdx.x;
    if (i < N_EDGES) {
        atomicAdd(&outdeg_i[src[i]], 1u);
        atomicAdd(&indeg_i[dst[i]], 1u);
    }
    if (i < N_NODES) {
        int g = gid[i];
        if (i == 0) {
            for (int x = 0; x <= g; ++x) start[x] = 0;
        } else {
            int gp = gid[i - 1];
            if (gp != g)
                for (int x = gp + 1; x <= g; ++x) start[x] = i;
        }
        if (i == N_NODES - 1)
            for (int x = g + 1; x <= N_GRAPHS; ++x) start[x] = N_NODES;
    }
}

// ---- scan pass 1 (+ norms folded in) ----------------------------------------
__global__ __launch_bounds__(256) void k_scan1(const unsigned* __restrict__ indeg_i,
                                               const unsigned* __restrict__ outdeg_i,
                                               unsigned* __restrict__ row_ptr,
                                               unsigned* __restrict__ blockSums,
                                               float* __restrict__ outnorm,
                                               float* __restrict__ innorm) {
    __shared__ unsigned s[256];
    int t = threadIdx.x;
    int i = blockIdx.x * 256 + t;
    unsigned val = (i < N_NODES) ? indeg_i[i] : 0u;
    if (i < N_NODES) {
        outnorm[i] = rsqrtf(fmaxf((float)outdeg_i[i], 1.0f));
        innorm[i]  = rsqrtf(fmaxf((float)val, 1.0f));
    }
    s[t] = val;
    __syncthreads();
    for (int off = 1; off < 256; off <<= 1) {
        unsigned x = (t >= off) ? s[t - off] : 0u;
        __syncthreads();
        s[t] += x;
        __syncthreads();
    }
    if (i < N_NODES) row_ptr[i] = s[t] - val;
    if (t == 255) blockSums[blockIdx.x] = s[255];
}

__global__ __launch_bounds__(256) void k_scan2(unsigned* __restrict__ blockSums,
                                               unsigned* __restrict__ blockOff) {
    __shared__ unsigned s[256];
    int t = threadIdx.x;
    unsigned val = (t < NB_N) ? blockSums[t] : 0u;
    s[t] = val;
    __syncthreads();
    for (int off = 1; off < 256; off <<= 1) {
        unsigned x = (t >= off) ? s[t - off] : 0u;
        __syncthreads();
        s[t] += x;
        __syncthreads();
    }
    if (t < NB_N) blockOff[t] = s[t] - val;
}

__global__ __launch_bounds__(256) void k_scan3(unsigned* __restrict__ row_ptr,
                                               const unsigned* __restrict__ blockOff) {
    int i = blockIdx.x * 256 + threadIdx.x;
    if (i < N_NODES) row_ptr[i] += blockOff[i >> 8];
}

// ---- bucket edges by dst ----------------------------------------------------
__global__ __launch_bounds__(256) void k_bucket(const int* __restrict__ src,
                                                const int* __restrict__ dst,
                                                const unsigned* __restrict__ row_ptr,
                                                unsigned* __restrict__ cursor,
                                                int* __restrict__ bsrc) {
    int e = blockIdx.x * 256 + threadIdx.x;
    if (e < N_EDGES) {
        int d = dst[e];
        unsigned p = atomicAdd(&cursor[d], 1u);
        bsrc[row_ptr[d] + p] = src[e];
    }
}

// ---- gather-sum: agg[n] = innorm[n] * sum_{e: dst=n} feat[src_e]*outnorm[src_e]
__global__ __launch_bounds__(256) void k_gather(const int* __restrict__ bsrc,
                                                const unsigned* __restrict__ row_ptr,
                                                const unsigned* __restrict__ indeg_i,
                                                const float* __restrict__ feat,
                                                const float* __restrict__ outnorm,
                                                const float* __restrict__ innorm,
                                                float* __restrict__ agg) {
    int tid = threadIdx.x;
    int wave = tid >> 6;
    int lane = tid & 63;
    int node = blockIdx.x * 4 + wave;
    if (node >= N_NODES) return;
    unsigned start = row_ptr[node];
    unsigned deg   = indeg_i[node];
    int half = lane >> 5;
    int q    = (lane & 31) << 2;
    float4 acc = {0.f, 0.f, 0.f, 0.f};
    for (unsigned j = 0; j < deg; j += 2) {
        unsigned jj = j + half;
        bool valid = (jj < deg);
        int s = bsrc[start + (valid ? jj : 0u)];
        float nrm = valid ? outnorm[s] : 0.0f;
        float4 v = *reinterpret_cast<const float4*>(feat + (size_t)s * DIM + q);
        acc.x += v.x * nrm;
        acc.y += v.y * nrm;
        acc.z += v.z * nrm;
        acc.w += v.w * nrm;
    }
    acc.x += __shfl_down(acc.x, 32);
    acc.y += __shfl_down(acc.y, 32);
    acc.z += __shfl_down(acc.z, 32);
    acc.w += __shfl_down(acc.w, 32);
    if (half == 0) {
        float innrm = innorm[node];
        float4 r = {acc.x * innrm, acc.y * innrm, acc.z * innrm, acc.w * innrm};
        *reinterpret_cast<float4*>(agg + (size_t)node * DIM + q) = r;
    }
}

#define FMA4(ACC, S, WV) ACC.x += (S) * WV.x; ACC.y += (S) * WV.y; \
                         ACC.z += (S) * WV.z; ACC.w += (S) * WV.w;

// ---- node transform: h = relu(agg @ W + b), in place. 4 nodes x 4 outs/thread
__global__ __launch_bounds__(256) void k_node(float* __restrict__ agg,
                                              const float* __restrict__ W,
                                              const float* __restrict__ b) {
    __shared__ float sW[DIM * DIM];        // 64 KB
    __shared__ float srow[PASSN][DIM];     // 16 KB
    int tid = threadIdx.x;
    for (int i = tid; i < DIM * DIM; i += 256) sW[i] = W[i];

    int o  = (tid & 31) << 2;   // output-dim base (0..124)
    int n0 = (tid >> 5) << 2;   // node slot base within pass (0..28)
    float4 bb = *reinterpret_cast<const float4*>(b + o);

    int blockBase = blockIdx.x * NPB;
    for (int p = 0; p < NPB / PASSN; ++p) {
        int base = blockBase + p * PASSN;
        __syncthreads();
        // stage 32 node rows; lanes 0-31 cover one contiguous row each iter
        for (int i = tid; i < PASSN * 32; i += 256) {
            int n = i >> 5, d4 = (i & 31) << 2;
            int node = base + n;
            float4 v = {0.f, 0.f, 0.f, 0.f};
            if (node < N_NODES)
                v = *reinterpret_cast<const float4*>(agg + (size_t)node * DIM + d4);
            *reinterpret_cast<float4*>(&srow[n][d4]) = v;
        }
        __syncthreads();
        float4 acc0 = {0,0,0,0}, acc1 = {0,0,0,0}, acc2 = {0,0,0,0}, acc3 = {0,0,0,0};
#pragma unroll 4
        for (int k = 0; k < DIM; k += 4) {
            float4 w0 = *reinterpret_cast<const float4*>(&sW[(k + 0) * DIM + o]);
            float4 w1 = *reinterpret_cast<const float4*>(&sW[(k + 1) * DIM + o]);
            float4 w2 = *reinterpret_cast<const float4*>(&sW[(k + 2) * DIM + o]);
            float4 w3 = *reinterpret_cast<const float4*>(&sW[(k + 3) * DIM + o]);
            float4 a0 = *reinterpret_cast<const float4*>(&srow[n0 + 0][k]);
            float4 a1 = *reinterpret_cast<const float4*>(&srow[n0 + 1][k]);
            float4 a2 = *reinterpret_cast<const float4*>(&srow[n0 + 2][k]);
            float4 a3 = *reinterpret_cast<const float4*>(&srow[n0 + 3][k]);
            FMA4(acc0, a0.x, w0); FMA4(acc0, a0.y, w1); FMA4(acc0, a0.z, w2); FMA4(acc0, a0.w, w3);
            FMA4(acc1, a1.x, w0); FMA4(acc1, a1.y, w1); FMA4(acc1, a1.z, w2); FMA4(acc1, a1.w, w3);
            FMA4(acc2, a2.x, w0); FMA4(acc2, a2.y, w1); FMA4(acc2, a2.z, w2); FMA4(acc2, a2.w, w3);
            FMA4(acc3, a3.x, w0); FMA4(acc3, a3.y, w1); FMA4(acc3, a3.z, w2); FMA4(acc3, a3.w, w3);
        }
        __syncthreads();  // all reads of srow done before overwrite below/next pass
        float4 accs[4] = {acc0, acc1, acc2, acc3};
#pragma unroll
        for (int j = 0; j < 4; ++j) {
            int node = base + n0 + j;
            if (node < N_NODES) {
                float4 h;
                h.x = fmaxf(accs[j].x + bb.x, 0.0f);
                h.y = fmaxf(accs[j].y + bb.y, 0.0f);
                h.z = fmaxf(accs[j].z + bb.z, 0.0f);
                h.w = fmaxf(accs[j].w + bb.w, 0.0f);
                *reinterpret_cast<float4*>(agg + (size_t)node * DIM + o) = h;
            }
        }
    }
}

// ---- graph sum-pool, parallel: grid (G, NCHUNK); atomics into zeroed pooled -
__global__ __launch_bounds__(256) void k_pool(const float* __restrict__ h,
                                              const int* __restrict__ start,
                                              float* __restrict__ pooled) {
    __shared__ float red[8][DIM];
    int g = blockIdx.x;
    int chunk = blockIdx.y;
    int t = threadIdx.x;
    int slot = t >> 5;
    int q    = (t & 31) << 2;
    int s = start[g], e = start[g + 1];
    float4 acc = {0.f, 0.f, 0.f, 0.f};
    for (int n = s + chunk * 8 + slot; n < e; n += NCHUNK * 8) {
        float4 v = *reinterpret_cast<const float4*>(h + (size_t)n * DIM + q);
        acc.x += v.x; acc.y += v.y; acc.z += v.z; acc.w += v.w;
    }
    *reinterpret_cast<float4*>(&red[slot][q]) = acc;
    __syncthreads();
    if (t < DIM) {
        float sum = 0.f;
#pragma unroll
        for (int r = 0; r < 8; ++r) sum += red[r][t];
        atomicAdd(&pooled[g * DIM + t], sum);
    }
}

// ---- head: out = (pooled/cnt) @ W_head + b_head -----------------------------
__global__ __launch_bounds__(256) void k_head(const float* __restrict__ pooled,
                                              const int* __restrict__ start,
                                              const float* __restrict__ Wh,
                                              const float* __restrict__ bh,
                                              float* __restrict__ out) {
    int i = blockIdx.x * 256 + threadIdx.x;
    if (i >= N_GRAPHS * N_CLASSES) return;
    int g = i / N_CLASSES, c = i % N_CLASSES;
    const float* pr = pooled + g * DIM;
    float s = 0.f;
#pragma unroll 8
    for (int k = 0; k < DIM; ++k) s += pr[k] * Wh[k * N_CLASSES + c];
    float cntf = fmaxf((float)(start[g + 1] - start[g]), 1.0f);
    out[i] = s / cntf + bh[c];
}

extern "C" void kernel_launch(void* const* d_in, const int* in_sizes, int n_in,
                              void* d_out, int out_size, void* d_ws, size_t ws_size,
                              hipStream_t stream) {
    const float* feat = (const float*)d_in[0];
    const int*   src  = (const int*)d_in[1];
    const int*   dst  = (const int*)d_in[2];
    const int*   gid  = (const int*)d_in[3];
    const float* W    = (const float*)d_in[4];
    const float* b    = (const float*)d_in[5];
    const float* Wh   = (const float*)d_in[6];
    const float* bh   = (const float*)d_in[7];
    float* out = (float*)d_out;

    // ---- workspace layout (4-byte elements) ----
    unsigned* cursor   = (unsigned*)d_ws;
    unsigned* outdeg_i = cursor + N_NODES;
    unsigned* indeg_i  = outdeg_i + N_NODES;
    float*    pooled   = (float*)(indeg_i + N_NODES);        // G*D
    size_t zero_bytes = ((size_t)3 * N_NODES + (size_t)N_GRAPHS * DIM) * 4;
    int*      start     = (int*)(pooled + (size_t)N_GRAPHS * DIM); // G+1
    unsigned* row_ptr   = (unsigned*)(start + N_GRAPHS + 1);
    unsigned* blockSums = row_ptr + N_NODES;
    unsigned* blockOff  = blockSums + 256;
    int*      bsrc      = (int*)(blockOff + 256);
    float*    outnorm   = (float*)(bsrc + N_EDGES);
    float*    innorm    = outnorm + N_NODES;
    float*    agg       = innorm + N_NODES;                  // N*D, reused as h

    hipMemsetAsync(d_ws, 0, zero_bytes, stream);

    k_deg   <<<(N_EDGES + 255) / 256, 256, 0, stream>>>(src, dst, gid, outdeg_i, indeg_i, start);
    k_scan1 <<<NB_N, 256, 0, stream>>>(indeg_i, outdeg_i, row_ptr, blockSums, outnorm, innorm);
    k_scan2 <<<1, 256, 0, stream>>>(blockSums, blockOff);
    k_scan3 <<<NB_N, 256, 0, stream>>>(row_ptr, blockOff);
    k_bucket<<<(N_EDGES + 255) / 256, 256, 0, stream>>>(src, dst, row_ptr, cursor, bsrc);
    k_gather<<<(N_NODES + 3) / 4, 256, 0, stream>>>(bsrc, row_ptr, indeg_i, feat, outnorm, innorm, agg);
    k_node  <<<(N_NODES + NPB - 1) / NPB, 256, 0, stream>>>(agg, W, b);
    dim3 pg(N_GRAPHS, NCHUNK);
    k_pool  <<<pg, 256, 0, stream>>>(agg, start, pooled);
    k_head  <<<3, 256, 0, stream>>>(pooled, start, Wh, bh, out);
}

// Round 6
// 280.648 us; speedup vs baseline: 6.6342x; 1.1108x over previous
//
#include <hip/hip_runtime.h>

#define N_NODES   50000
#define N_EDGES   800000
#define DIM       128
#define N_GRAPHS  64
#define N_CLASSES 10
#define NB_N      ((N_NODES + 255) / 256)   // 196
#define NCHUNK    16
#define NPB       128   // nodes per block in k_node
#define PASSN     32    // nodes staged per pass
#define NREP      4     // histogram replication

// ---- replicated degree histograms + bucket cursor fused + graph boundaries --
// perm[e] = this edge's slot within (replica, dst) bucket. Replica = e&3
// spreads same-sector atomic conflicts 4x. graph_ids sorted -> boundary scan.
__global__ __launch_bounds__(256) void k_hist(const int* __restrict__ src,
                                              const int* __restrict__ dst,
                                              const int* __restrict__ gid,
                                              unsigned* __restrict__ indegR,
                                              unsigned* __restrict__ outdegR,
                                              unsigned* __restrict__ perm,
                                              int* __restrict__ start) {
    int i = blockIdx.x * 256 + threadIdx.x;
    if (i < N_EDGES) {
        int r = i & (NREP - 1);
        int d = dst[i], s = src[i];
        perm[i] = atomicAdd(&indegR[(size_t)r * N_NODES + d], 1u);
        atomicAdd(&outdegR[(size_t)r * N_NODES + s], 1u);
    }
    if (i < N_NODES) {
        int g = gid[i];
        if (i == 0) {
            for (int x = 0; x <= g; ++x) start[x] = 0;
        } else {
            int gp = gid[i - 1];
            if (gp != g)
                for (int x = gp + 1; x <= g; ++x) start[x] = i;
        }
        if (i == N_NODES - 1)
            for (int x = g + 1; x <= N_GRAPHS; ++x) start[x] = N_NODES;
    }
}

// ---- reduce replicas -> totals, per-replica prefixes, norms -----------------
__global__ __launch_bounds__(256) void k_reduce(const unsigned* __restrict__ indegR,
                                                const unsigned* __restrict__ outdegR,
                                                unsigned* __restrict__ indeg,
                                                unsigned* __restrict__ preIn,
                                                float* __restrict__ outnorm,
                                                float* __restrict__ innorm) {
    int i = blockIdx.x * 256 + threadIdx.x;
    if (i >= N_NODES) return;
    unsigned c0 = indegR[i];
    unsigned c1 = indegR[(size_t)N_NODES + i];
    unsigned c2 = indegR[(size_t)2 * N_NODES + i];
    unsigned c3 = indegR[(size_t)3 * N_NODES + i];
    preIn[i] = 0u;
    preIn[(size_t)N_NODES + i] = c0;
    preIn[(size_t)2 * N_NODES + i] = c0 + c1;
    preIn[(size_t)3 * N_NODES + i] = c0 + c1 + c2;
    unsigned tot = c0 + c1 + c2 + c3;
    indeg[i] = tot;
    innorm[i] = rsqrtf(fmaxf((float)tot, 1.0f));
    unsigned od = outdegR[i] + outdegR[(size_t)N_NODES + i]
                + outdegR[(size_t)2 * N_NODES + i] + outdegR[(size_t)3 * N_NODES + i];
    outnorm[i] = rsqrtf(fmaxf((float)od, 1.0f));
}

// ---- exclusive scan over indeg -> row_ptr (3 kernels) -----------------------
__global__ __launch_bounds__(256) void k_scan1(const unsigned* __restrict__ indeg,
                                               unsigned* __restrict__ row_ptr,
                                               unsigned* __restrict__ blockSums) {
    __shared__ unsigned s[256];
    int t = threadIdx.x;
    int i = blockIdx.x * 256 + t;
    unsigned val = (i < N_NODES) ? indeg[i] : 0u;
    s[t] = val;
    __syncthreads();
    for (int off = 1; off < 256; off <<= 1) {
        unsigned x = (t >= off) ? s[t - off] : 0u;
        __syncthreads();
        s[t] += x;
        __syncthreads();
    }
    if (i < N_NODES) row_ptr[i] = s[t] - val;
    if (t == 255) blockSums[blockIdx.x] = s[255];
}

__global__ __launch_bounds__(256) void k_scan2(unsigned* __restrict__ blockSums,
                                               unsigned* __restrict__ blockOff) {
    __shared__ unsigned s[256];
    int t = threadIdx.x;
    unsigned val = (t < NB_N) ? blockSums[t] : 0u;
    s[t] = val;
    __syncthreads();
    for (int off = 1; off < 256; off <<= 1) {
        unsigned x = (t >= off) ? s[t - off] : 0u;
        __syncthreads();
        s[t] += x;
        __syncthreads();
    }
    if (t < NB_N) blockOff[t] = s[t] - val;
}

__global__ __launch_bounds__(256) void k_scan3(unsigned* __restrict__ row_ptr,
                                               const unsigned* __restrict__ blockOff) {
    int i = blockIdx.x * 256 + threadIdx.x;
    if (i < N_NODES) row_ptr[i] += blockOff[i >> 8];
}

// ---- scatter edges into CSR buckets — NO atomics ---------------------------
__global__ __launch_bounds__(256) void k_scatter(const int* __restrict__ src,
                                                 const int* __restrict__ dst,
                                                 const unsigned* __restrict__ row_ptr,
                                                 const unsigned* __restrict__ preIn,
                                                 const unsigned* __restrict__ perm,
                                                 int* __restrict__ bsrc) {
    int e = blockIdx.x * 256 + threadIdx.x;
    if (e < N_EDGES) {
        int r = e & (NREP - 1);
        int d = dst[e];
        unsigned pos = row_ptr[d] + preIn[(size_t)r * N_NODES + d] + perm[e];
        bsrc[pos] = src[e];
    }
}

// ---- gather-sum: agg[n] = innorm[n] * sum_{e: dst=n} feat[src_e]*outnorm[src_e]
// One wave per node; unrolled 4 edges/iter (two independent load chains).
__global__ __launch_bounds__(256) void k_gather(const int* __restrict__ bsrc,
                                                const unsigned* __restrict__ row_ptr,
                                                const unsigned* __restrict__ indeg,
                                                const float* __restrict__ feat,
                                                const float* __restrict__ outnorm,
                                                const float* __restrict__ innorm,
                                                float* __restrict__ agg) {
    int tid = threadIdx.x;
    int wave = tid >> 6;
    int lane = tid & 63;
    int node = blockIdx.x * 4 + wave;
    if (node >= N_NODES) return;
    unsigned start = row_ptr[node];
    unsigned deg   = indeg[node];
    int half = lane >> 5;
    int q    = (lane & 31) << 2;
    float4 acc  = {0.f, 0.f, 0.f, 0.f};
    float4 acc2 = {0.f, 0.f, 0.f, 0.f};
    unsigned j = 0;
    for (; j + 4 <= deg; j += 4) {
        int s0 = bsrc[start + j + half];
        int s1 = bsrc[start + j + 2 + half];
        float n0 = outnorm[s0];
        float n1 = outnorm[s1];
        float4 v0 = *reinterpret_cast<const float4*>(feat + (size_t)s0 * DIM + q);
        float4 v1 = *reinterpret_cast<const float4*>(feat + (size_t)s1 * DIM + q);
        acc.x  += v0.x * n0; acc.y  += v0.y * n0; acc.z  += v0.z * n0; acc.w  += v0.w * n0;
        acc2.x += v1.x * n1; acc2.y += v1.y * n1; acc2.z += v1.z * n1; acc2.w += v1.w * n1;
    }
    for (; j < deg; j += 2) {
        unsigned jj = j + half;
        bool valid = (jj < deg);
        int s = bsrc[start + (valid ? jj : 0u)];
        float nrm = valid ? outnorm[s] : 0.0f;
        float4 v = *reinterpret_cast<const float4*>(feat + (size_t)s * DIM + q);
        acc.x += v.x * nrm; acc.y += v.y * nrm; acc.z += v.z * nrm; acc.w += v.w * nrm;
    }
    acc.x += acc2.x; acc.y += acc2.y; acc.z += acc2.z; acc.w += acc2.w;
    acc.x += __shfl_down(acc.x, 32);
    acc.y += __shfl_down(acc.y, 32);
    acc.z += __shfl_down(acc.z, 32);
    acc.w += __shfl_down(acc.w, 32);
    if (half == 0) {
        float innrm = innorm[node];
        float4 r = {acc.x * innrm, acc.y * innrm, acc.z * innrm, acc.w * innrm};
        *reinterpret_cast<float4*>(agg + (size_t)node * DIM + q) = r;
    }
}

#define FMA4(ACC, S, WV) ACC.x += (S) * WV.x; ACC.y += (S) * WV.y; \
                         ACC.z += (S) * WV.z; ACC.w += (S) * WV.w;

// ---- node transform: h = relu(agg @ W + b), in place. 4 nodes x 4 outs/thread
__global__ __launch_bounds__(256) void k_node(float* __restrict__ agg,
                                              const float* __restrict__ W,
                                              const float* __restrict__ b) {
    __shared__ float sW[DIM * DIM];        // 64 KB
    __shared__ float srow[PASSN][DIM];     // 16 KB
    int tid = threadIdx.x;
    for (int i = tid; i < DIM * DIM; i += 256) sW[i] = W[i];

    int o  = (tid & 31) << 2;
    int n0 = (tid >> 5) << 2;
    float4 bb = *reinterpret_cast<const float4*>(b + o);

    int blockBase = blockIdx.x * NPB;
    for (int p = 0; p < NPB / PASSN; ++p) {
        int base = blockBase + p * PASSN;
        __syncthreads();
        for (int i = tid; i < PASSN * 32; i += 256) {
            int n = i >> 5, d4 = (i & 31) << 2;
            int node = base + n;
            float4 v = {0.f, 0.f, 0.f, 0.f};
            if (node < N_NODES)
                v = *reinterpret_cast<const float4*>(agg + (size_t)node * DIM + d4);
            *reinterpret_cast<float4*>(&srow[n][d4]) = v;
        }
        __syncthreads();
        float4 acc0 = {0,0,0,0}, acc1 = {0,0,0,0}, acc2 = {0,0,0,0}, acc3 = {0,0,0,0};
#pragma unroll 4
        for (int k = 0; k < DIM; k += 4) {
            float4 w0 = *reinterpret_cast<const float4*>(&sW[(k + 0) * DIM + o]);
            float4 w1 = *reinterpret_cast<const float4*>(&sW[(k + 1) * DIM + o]);
            float4 w2 = *reinterpret_cast<const float4*>(&sW[(k + 2) * DIM + o]);
            float4 w3 = *reinterpret_cast<const float4*>(&sW[(k + 3) * DIM + o]);
            float4 a0 = *reinterpret_cast<const float4*>(&srow[n0 + 0][k]);
            float4 a1 = *reinterpret_cast<const float4*>(&srow[n0 + 1][k]);
            float4 a2 = *reinterpret_cast<const float4*>(&srow[n0 + 2][k]);
            float4 a3 = *reinterpret_cast<const float4*>(&srow[n0 + 3][k]);
            FMA4(acc0, a0.x, w0); FMA4(acc0, a0.y, w1); FMA4(acc0, a0.z, w2); FMA4(acc0, a0.w, w3);
            FMA4(acc1, a1.x, w0); FMA4(acc1, a1.y, w1); FMA4(acc1, a1.z, w2); FMA4(acc1, a1.w, w3);
            FMA4(acc2, a2.x, w0); FMA4(acc2, a2.y, w1); FMA4(acc2, a2.z, w2); FMA4(acc2, a2.w, w3);
            FMA4(acc3, a3.x, w0); FMA4(acc3, a3.y, w1); FMA4(acc3, a3.z, w2); FMA4(acc3, a3.w, w3);
        }
        __syncthreads();
        float4 accs[4] = {acc0, acc1, acc2, acc3};
#pragma unroll
        for (int j = 0; j < 4; ++j) {
            int node = base + n0 + j;
            if (node < N_NODES) {
                float4 h;
                h.x = fmaxf(accs[j].x + bb.x, 0.0f);
                h.y = fmaxf(accs[j].y + bb.y, 0.0f);
                h.z = fmaxf(accs[j].z + bb.z, 0.0f);
                h.w = fmaxf(accs[j].w + bb.w, 0.0f);
                *reinterpret_cast<float4*>(agg + (size_t)node * DIM + o) = h;
            }
        }
    }
}

// ---- graph sum-pool, parallel: grid (G, NCHUNK); atomics into zeroed pooled -
__global__ __launch_bounds__(256) void k_pool(const float* __restrict__ h,
                                              const int* __restrict__ start,
                                              float* __restrict__ pooled) {
    __shared__ float red[8][DIM];
    int g = blockIdx.x;
    int chunk = blockIdx.y;
    int t = threadIdx.x;
    int slot = t >> 5;
    int q    = (t & 31) << 2;
    int s = start[g], e = start[g + 1];
    float4 acc = {0.f, 0.f, 0.f, 0.f};
    for (int n = s + chunk * 8 + slot; n < e; n += NCHUNK * 8) {
        float4 v = *reinterpret_cast<const float4*>(h + (size_t)n * DIM + q);
        acc.x += v.x; acc.y += v.y; acc.z += v.z; acc.w += v.w;
    }
    *reinterpret_cast<float4*>(&red[slot][q]) = acc;
    __syncthreads();
    if (t < DIM) {
        float sum = 0.f;
#pragma unroll
        for (int r = 0; r < 8; ++r) sum += red[r][t];
        atomicAdd(&pooled[g * DIM + t], sum);
    }
}

// ---- head: out = (pooled/cnt) @ W_head + b_head -----------------------------
__global__ __launch_bounds__(256) void k_head(const float* __restrict__ pooled,
                                              const int* __restrict__ start,
                                              const float* __restrict__ Wh,
                                              const float* __restrict__ bh,
                                              float* __restrict__ out) {
    int i = blockIdx.x * 256 + threadIdx.x;
    if (i >= N_GRAPHS * N_CLASSES) return;
    int g = i / N_CLASSES, c = i % N_CLASSES;
    const float* pr = pooled + g * DIM;
    float s = 0.f;
#pragma unroll 8
    for (int k = 0; k < DIM; ++k) s += pr[k] * Wh[k * N_CLASSES + c];
    float cntf = fmaxf((float)(start[g + 1] - start[g]), 1.0f);
    out[i] = s / cntf + bh[c];
}

extern "C" void kernel_launch(void* const* d_in, const int* in_sizes, int n_in,
                              void* d_out, int out_size, void* d_ws, size_t ws_size,
                              hipStream_t stream) {
    const float* feat = (const float*)d_in[0];
    const int*   src  = (const int*)d_in[1];
    const int*   dst  = (const int*)d_in[2];
    const int*   gid  = (const int*)d_in[3];
    const float* W    = (const float*)d_in[4];
    const float* b    = (const float*)d_in[5];
    const float* Wh   = (const float*)d_in[6];
    const float* bh   = (const float*)d_in[7];
    float* out = (float*)d_out;

    // ---- workspace layout (4-byte elements) ----
    // zeroed: indegR[4N], outdegR[4N], pooled[G*D]
    unsigned* indegR  = (unsigned*)d_ws;
    unsigned* outdegR = indegR + (size_t)NREP * N_NODES;
    float*    pooled  = (float*)(outdegR + (size_t)NREP * N_NODES);
    size_t zero_bytes = ((size_t)2 * NREP * N_NODES + (size_t)N_GRAPHS * DIM) * 4;
    // non-zeroed
    unsigned* indeg     = (unsigned*)(pooled + (size_t)N_GRAPHS * DIM); // N
    unsigned* preIn     = indeg + N_NODES;                              // 4N
    int*      start     = (int*)(preIn + (size_t)NREP * N_NODES);       // G+1
    unsigned* row_ptr   = (unsigned*)(start + N_GRAPHS + 1);            // N
    unsigned* blockSums = row_ptr + N_NODES;                            // 256
    unsigned* blockOff  = blockSums + 256;                              // 256
    unsigned* perm      = blockOff + 256;                               // E
    int*      bsrc      = (int*)(perm + N_EDGES);                       // E
    float*    outnorm   = (float*)(bsrc + N_EDGES);                     // N
    float*    innorm    = outnorm + N_NODES;                            // N
    float*    agg       = innorm + N_NODES;                             // N*D

    hipMemsetAsync(d_ws, 0, zero_bytes, stream);

    k_hist   <<<(N_EDGES + 255) / 256, 256, 0, stream>>>(src, dst, gid, indegR, outdegR, perm, start);
    k_reduce <<<NB_N, 256, 0, stream>>>(indegR, outdegR, indeg, preIn, outnorm, innorm);
    k_scan1  <<<NB_N, 256, 0, stream>>>(indeg, row_ptr, blockSums);
    k_scan2  <<<1, 256, 0, stream>>>(blockSums, blockOff);
    k_scan3  <<<NB_N, 256, 0, stream>>>(row_ptr, blockOff);
    k_scatter<<<(N_EDGES + 255) / 256, 256, 0, stream>>>(src, dst, row_ptr, preIn, perm, bsrc);
    k_gather <<<(N_NODES + 3) / 4, 256, 0, stream>>>(bsrc, row_ptr, indeg, feat, outnorm, innorm, agg);
    k_node   <<<(N_NODES + NPB - 1) / NPB, 256, 0, stream>>>(agg, W, b);
    dim3 pg(N_GRAPHS, NCHUNK);
    k_pool   <<<pg, 256, 0, stream>>>(agg, start, pooled);
    k_head   <<<3, 256, 0, stream>>>(pooled, start, Wh, bh, out);
}